// Round 1
// baseline (358.923 us; speedup 1.0000x reference)
//
#include <hip/hip_runtime.h>

// Superpixel max-pool: out[b][c][k] = max over pixels (h,w) with spx[b,h,w]==k of img[b][c][h,w].
// Strategy: LDS privatization with exclusive output ownership.
//   grid = B(8) x channel-groups(64), each block handles CSUB=2 channels over all HW pixels
//   of one batch -> owns out[b][c0:c0+2][:] exclusively (no global atomics, no init pass).
// Float max via order-preserving uint mapping -> native ds_max_u32 (exact, bitwise).

#define NTHREADS 1024

constexpr int B_ = 8, C_ = 128, H_ = 256, W_ = 256, K_ = 1024;
constexpr int HW_ = H_ * W_;        // 65536
constexpr int CSUB = 2;             // channels per block
constexpr int CGRP = C_ / CSUB;     // 64 channel-groups per batch
constexpr int STRIDE = CSUB + 1;    // 3: odd -> (label*3+c)%32 spreads LDS banks

// order-preserving float->uint: monotone, so uint max == float max
__device__ __forceinline__ unsigned f2o(float f) {
    unsigned u = __float_as_uint(f);
    return u ^ (unsigned)(((int)u >> 31) | (int)0x80000000);
}
__device__ __forceinline__ float o2f(unsigned o) {
    return __uint_as_float(o ^ (((int)o >= 0) ? 0xFFFFFFFFu : 0x80000000u));
}

__global__ __launch_bounds__(NTHREADS) void SupPixPool_25366076850473_kernel(
    const float* __restrict__ img, const int* __restrict__ spx, float* __restrict__ out)
{
    __shared__ unsigned smax[K_ * STRIDE];   // 12 KB
    const int tid = threadIdx.x;

    // init to f2o(-inf) = 0x007FFFFF so empty segments produce -inf (segment_max semantics)
    for (int i = tid; i < K_ * STRIDE; i += NTHREADS)
        smax[i] = 0x007FFFFFu;
    __syncthreads();

    const int b  = blockIdx.x / CGRP;
    const int cg = blockIdx.x % CGRP;
    const int c0 = cg * CSUB;

    const int4*  lab4 = (const int4*)(spx + (size_t)b * HW_);
    const float* imgb = img + ((size_t)(b * C_ + c0)) * HW_;
    constexpr int NV = HW_ / 4;              // 16384 vec4 groups

    for (int v = tid; v < NV; v += NTHREADS) {
        int4 lab = lab4[v];                  // labels reused for both channels
        int a0 = lab.x * STRIDE, a1 = lab.y * STRIDE,
            a2 = lab.z * STRIDE, a3 = lab.w * STRIDE;
#pragma unroll
        for (int c = 0; c < CSUB; ++c) {
            float4 x = ((const float4*)(imgb + (size_t)c * HW_))[v];
            atomicMax(&smax[a0 + c], f2o(x.x));
            atomicMax(&smax[a1 + c], f2o(x.y));
            atomicMax(&smax[a2 + c], f2o(x.z));
            atomicMax(&smax[a3 + c], f2o(x.w));
        }
    }
    __syncthreads();

    // exclusive epilogue: this block owns out[b][c0..c0+CSUB)[*]
    float* outb = out + ((size_t)(b * C_ + c0)) * K_;
    for (int i = tid; i < K_ * CSUB; i += NTHREADS) {
        int c = i >> 10;                     // K_ = 1024
        int k = i & (K_ - 1);
        outb[c * K_ + k] = o2f(smax[k * STRIDE + c]);
    }
}

extern "C" void kernel_launch(void* const* d_in, const int* in_sizes, int n_in,
                              void* d_out, int out_size, void* d_ws, size_t ws_size,
                              hipStream_t stream) {
    const float* img = (const float*)d_in[0];
    const int*   spx = (const int*)d_in[1];
    float*       out = (float*)d_out;        // fp32 output, [B][C][K]
    // d_in[2] is K (scalar on device) -- problem constants are fixed, K_=1024 hardcoded.
    dim3 grid(B_ * CGRP);                    // 512 blocks -> 2 blocks/CU, 32 waves/CU
    hipLaunchKernelGGL(SupPixPool_25366076850473_kernel, grid, dim3(NTHREADS), 0, stream,
                       img, spx, out);
}